// Round 16
// baseline (805.153 us; speedup 1.0000x reference)
//
#include <hip/hip_runtime.h>
#include <stdint.h>

#define BB 4
#define NN 8192
#define KK 16
#define BN (BB*NN)        // 32768
#define BNK (BN*KK)       // 524288

// ---------------- K0: pack xyz -> (x,y,z,|p|^2) float4 ----------------
__global__ void k_xyzw(const float* __restrict__ xyz1, const float* __restrict__ xyz2,
                       float4* __restrict__ w1, float4* __restrict__ w2){
    int t = blockIdx.x*256 + threadIdx.x;
    if (t >= 2*BN) return;
    const float* src; float4* dst; int i;
    if (t < BN){ src = xyz1; dst = w1; i = t; }
    else       { src = xyz2; dst = w2; i = t - BN; }
    int b = i >> 13, m = i & (NN-1);
    const float* p = src + (size_t)b*3*NN + m;
    float x = p[0], y = p[NN], z = p[2*NN];
    dst[i] = make_float4(x, y, z, x*x + y*y + z*z);
}

// ------------- K1: merged prefeat: A[half][b,n,co] = bias + W1[:,colOff:colOff+64]*feat -------------
__global__ __launch_bounds__(256) void k_prefeat(const float* __restrict__ feat1,
                                                 const float* __restrict__ feat2,
                                                 const float* __restrict__ W1,
                                                 const float* __restrict__ bias,
                                                 float* __restrict__ A1, float* __restrict__ A2){
    __shared__ float Wt[64*64];   // [ci][co]
    __shared__ float bsh[64];
    int tid = threadIdx.x;
    int lane = tid & 63;
    int wv = tid >> 6;
    int half = blockIdx.x >> 7;                  // 0: feat1->A1 (bias), 1: feat2->A2
    int colOff = half ? 64 : 0;
    const float* feat = half ? feat2 : feat1;
    float* out = half ? A2 : A1;

    for (int i = tid; i < 4096; i += 256){
        int co = i >> 6, ci = i & 63;
        Wt[ci*64 + co] = W1[co*131 + colOff + ci];
    }
    if (tid < 64) bsh[tid] = half ? 0.0f : bias[tid];
    __syncthreads();

    int col = (blockIdx.x & 127)*256 + wv*64 + lane;   // (b,n) flat
    int b = col >> 13, n = col & (NN-1);
    const float* f = feat + (size_t)b*64*NN + n;
    float acc[64];
    #pragma unroll
    for (int co = 0; co < 64; ++co) acc[co] = 0.f;
    for (int ci = 0; ci < 64; ++ci){
        float v = f[(size_t)ci*NN];
        const float4* wrow = (const float4*)(Wt + ci*64);
        #pragma unroll
        for (int c4 = 0; c4 < 16; ++c4){
            float4 w = wrow[c4];
            acc[c4*4+0] = fmaf(w.x, v, acc[c4*4+0]);
            acc[c4*4+1] = fmaf(w.y, v, acc[c4*4+1]);
            acc[c4*4+2] = fmaf(w.z, v, acc[c4*4+2]);
            acc[c4*4+3] = fmaf(w.w, v, acc[c4*4+3]);
        }
    }
    float4* o = (float4*)(out + (size_t)col*64);
    const float4* bs = (const float4*)bsh;
    #pragma unroll
    for (int c4 = 0; c4 < 16; ++c4){
        float4 bb = bs[c4];
        o[c4] = make_float4(acc[c4*4+0]+bb.x, acc[c4*4+1]+bb.y,
                            acc[c4*4+2]+bb.z, acc[c4*4+3]+bb.w);
    }
}

// ---------------- K2: exact 16-NN, two-phase ----------------
// Wave w owns chunk [1024w,1024w+1024) for the block's 64 queries (lane=query).
// Phase A: f32 value-only top-16 of the FULL chunk (exact chunk-16th) ->
//   per-query threshold = min over 8 chunks via LDS atomicMin ~ global 16th.
//   (r8 sampled 256 -> rank-64 threshold -> ~60 Phase-B survivors/lane; full
//   scan cuts survivors ~3x, collapsing divergent f64+ladder flush cost.)
// Phase B: full rescan with tight threshold; survivors f64-verified into
//   packed-u64 register ladder (exact f64 ordering, top_k tie semantics).
#define SCAP 19
#define CHUNK 1024

__device__ __forceinline__ unsigned mono_f32(float f){
    unsigned u = __float_as_uint(f);
    return ((int)u >= 0) ? (u | 0x80000000u) : ~u;
}
__device__ __forceinline__ float unmono_f32(unsigned v){
    unsigned u = ((int)v < 0) ? (v & 0x7FFFFFFFu) : ~v;
    return __uint_as_float(u);
}
__device__ __forceinline__ unsigned long long mono_f64(double d){
    unsigned long long u = (unsigned long long)__double_as_longlong(d);
    return ((long long)u >= 0) ? (u | 0x8000000000000000ull) : ~u;
}
__device__ __forceinline__ double unmono_f64(unsigned long long v){
    unsigned long long u = ((long long)v < 0) ? (v & 0x7FFFFFFFFFFFFFFFull) : ~v;
    return __longlong_as_double((long long)u);
}

#define FSWAP(x,y) { float _a = fminf((x),(y)), _b = fmaxf((x),(y)); (x)=_a; (y)=_b; }
#define INSERT_F(t)                                                         \
    if ((t) < T15){                                                         \
        T15 = (t);                                                          \
        FSWAP(T14,T15) FSWAP(T13,T14) FSWAP(T12,T13) FSWAP(T11,T12)         \
        FSWAP(T10,T11) FSWAP(T9,T10)  FSWAP(T8,T9)   FSWAP(T7,T8)           \
        FSWAP(T6,T7)   FSWAP(T5,T6)   FSWAP(T4,T5)   FSWAP(T3,T4)           \
        FSWAP(T2,T3)   FSWAP(T1,T2)   FSWAP(T0,T1)                          \
    }

#define KSWAP(x,y) { unsigned long long _lo=(x), _hi=(y); bool _sw=_hi<_lo; (y)=_sw?_lo:_hi; (x)=_sw?_hi:_lo; }
#define INSERT_KEY(key)                                                     \
    if ((key) < A15){                                                       \
        A15 = (key);                                                        \
        KSWAP(A14,A15) KSWAP(A13,A14) KSWAP(A12,A13) KSWAP(A11,A12)         \
        KSWAP(A10,A11) KSWAP(A9,A10)  KSWAP(A8,A9)   KSWAP(A7,A8)           \
        KSWAP(A6,A7)   KSWAP(A5,A6)   KSWAP(A4,A5)   KSWAP(A3,A4)           \
        KSWAP(A2,A3)   KSWAP(A1,A2)   KSWAP(A0,A1)                          \
    }

__global__ __launch_bounds__(512, 2) void k_knn(const float4* __restrict__ qpts,
                                             const float4* __restrict__ cA, const float4* __restrict__ cB,
                                             int* __restrict__ outA, int* __restrict__ outB){
    __shared__ unsigned int thrsh[64];
    __shared__ __align__(16) char pool[38912];   // phase stacks / merge area unioned

    const float4* cpts = (blockIdx.y == 0) ? cA : cB;
    int* out            = (blockIdx.y == 0) ? outA : outB;

    int tid = threadIdx.x;
    int lane = tid & 63;
    int wv = tid >> 6;
    int gq = blockIdx.x*64 + lane;
    int b = gq >> 13;
    float4 q = qpts[gq];
    float n2x = -2.f*q.x, n2y = -2.f*q.y, n2z = -2.f*q.z;
    double qx = q.x, qy = q.y, qz = q.z;
    double qq = fma(qx,qx, fma(qy,qy, qz*qz));

    if (tid < 64) thrsh[tid] = 0xFF800000u;      // mono(+inf)
    __syncthreads();

    const float4* cb = cpts + (size_t)b*NN;
    int j0beg = wv*CHUNK;
    int cnt = 0;

    // ================= Phase A: exact f32 chunk-16th (values only, full chunk) =================
    {
        float T0,T1,T2,T3,T4,T5,T6,T7,T8,T9,T10,T11,T12,T13,T14,T15;
        const float FINF = __builtin_inff();
        T0=FINF;T1=FINF;T2=FINF;T3=FINF;T4=FINF;T5=FINF;T6=FINF;T7=FINF;
        T8=FINF;T9=FINF;T10=FINF;T11=FINF;T12=FINF;T13=FINF;T14=FINF;T15=FINF;
        float bdtA = FINF;
        float* stkf = ((float*)pool) + tid*SCAP;

        for (int jo = j0beg; jo < j0beg + CHUNK; jo += 4){
            const float4* cp = cb + jo;
            #pragma unroll
            for (int jj = 0; jj < 4; ++jj){
                float4 c = cp[jj];
                float t = fmaf(n2x, c.x, c.w);
                t = fmaf(n2y, c.y, t);
                t = fmaf(n2z, c.z, t);
                if (t < fminf(bdtA, T15)){ stkf[cnt] = t; cnt++; }
            }
            if (__any(cnt >= 16)){
                for (int s = 0; s < cnt; ++s){ float t = stkf[s]; INSERT_F(t) }
                cnt = 0;
                unsigned m = mono_f32(T15);
                unsigned old = atomicMin(&thrsh[lane], m);
                bdtA = unmono_f32(old < m ? old : m);
            }
        }
        for (int s = 0; s < cnt; ++s){ float t = stkf[s]; INSERT_F(t) }
        cnt = 0;
        atomicMin(&thrsh[lane], mono_f32(T15));
    }
    __syncthreads();     // all chunk-16ths published

    // ================= Phase B: exact rescan, tight screen =================
    const unsigned long long KINIT = 0xFFF0000000000000ull | 8191ull;  // mono(+inf)|idx
    unsigned long long A0=KINIT, A1=KINIT, A2=KINIT, A3=KINIT,
                       A4=KINIT, A5=KINIT, A6=KINIT, A7=KINIT,
                       A8=KINIT, A9=KINIT, A10=KINIT, A11=KINIT,
                       A12=KINIT, A13=KINIT, A14=KINIT, A15=KINIT;
    float bdt = unmono_f32(thrsh[lane]) + 1e-4f;   // margin >> f32 screen error
    int* stk = ((int*)pool) + tid*SCAP;

    #define FLUSH_B()                                                            \
        do {                                                                     \
            for (int s = 0; s < cnt; ++s){                                       \
                int j = stk[s];                                                  \
                float4 c = cb[j];                                                \
                double px = c.x, py = c.y, pz = c.z;                             \
                double pp  = fma(px,px, fma(py,py, pz*pz));                      \
                double dot = fma(qx,px, fma(qy,py, qz*pz));                      \
                double d2 = qq + pp - 2.0*dot;                                   \
                unsigned long long key =                                         \
                    (mono_f64(d2) & ~8191ull) | (unsigned long long)(unsigned)j; \
                INSERT_KEY(key)                                                  \
            }                                                                    \
            cnt = 0;                                                             \
            bdt = fminf(bdt, (float)(unmono_f64(A15) - qq) + 1e-4f);             \
        } while(0)

    for (int j0 = j0beg; j0 < j0beg + CHUNK; j0 += 4){
        const float4* cp = cb + j0;
        #pragma unroll
        for (int jj = 0; jj < 4; ++jj){
            float4 c = cp[jj];
            float t = fmaf(n2x, c.x, c.w);
            t = fmaf(n2y, c.y, t);
            t = fmaf(n2z, c.z, t);
            if (t < bdt){ stk[cnt] = j0 + jj; cnt++; }
        }
        if (__any(cnt >= 16)) FLUSH_B();         // max growth 4/group, SCAP=19 safe
    }
    FLUSH_B();

    __syncthreads();                             // stacks dead; pool becomes merge area
    unsigned long long* mrg = (unsigned long long*)pool;   // [4][64][17]
    #pragma unroll
    for (int r = 4; r >= 1; r >>= 1){
        if (wv >= r && wv < 2*r){
            unsigned long long* dst = mrg + ((size_t)(wv - r)*64 + lane)*17;
            dst[0]=A0;  dst[1]=A1;  dst[2]=A2;  dst[3]=A3;
            dst[4]=A4;  dst[5]=A5;  dst[6]=A6;  dst[7]=A7;
            dst[8]=A8;  dst[9]=A9;  dst[10]=A10; dst[11]=A11;
            dst[12]=A12; dst[13]=A13; dst[14]=A14; dst[15]=A15;
        }
        __syncthreads();
        if (wv < r){
            const unsigned long long* src = mrg + ((size_t)wv*64 + lane)*17;
            for (int i = 0; i < 16; ++i){
                unsigned long long bkey = src[i];
                if (__all(bkey >= A15)) break;       // uniform early-out
                INSERT_KEY(bkey)
            }
        }
        __syncthreads();
    }
    if (wv == 0){
        int4* o = (int4*)(out + (size_t)gq*16);
        o[0] = make_int4((int)(A0 & 8191ull),  (int)(A1 & 8191ull),
                         (int)(A2 & 8191ull),  (int)(A3 & 8191ull));
        o[1] = make_int4((int)(A4 & 8191ull),  (int)(A5 & 8191ull),
                         (int)(A6 & 8191ull),  (int)(A7 & 8191ull));
        o[2] = make_int4((int)(A8 & 8191ull),  (int)(A9 & 8191ull),
                         (int)(A10 & 8191ull), (int)(A11 & 8191ull));
        o[3] = make_int4((int)(A12 & 8191ull), (int)(A13 & 8191ull),
                         (int)(A14 & 8191ull), (int)(A15 & 8191ull));
    }
}

// ---------------- K3: merged small-MLP hidden states (both neighbor sets) ----------------
__global__ __launch_bounds__(256) void k_h2(const float4* __restrict__ xyzw1, const float4* __restrict__ xyzw2,
                                            const int* __restrict__ idx12, const int* __restrict__ idx11,
                                            const float* __restrict__ w1a, const float* __restrict__ b1a,
                                            const float* __restrict__ w2a, const float* __restrict__ b2a,
                                            const float* __restrict__ w1b, const float* __restrict__ b1b,
                                            const float* __restrict__ w2b, const float* __restrict__ b2b,
                                            float* __restrict__ H12, float* __restrict__ H11){
    int bset = blockIdx.x >> 11;                 // 0: idx12 (wn2->H12), 1: idx11 (wn1->H11)
    int i = (blockIdx.x & 2047)*256 + threadIdx.x;   // over BNK
    const int* idx = bset ? idx11 : idx12;
    const float4* cpts = bset ? xyzw1 : xyzw2;
    const float* w1 = bset ? w1b : w1a;  const float* b1 = bset ? b1b : b1a;
    const float* w2 = bset ? w2b : w2a;  const float* b2 = bset ? b2b : b2a;
    float* H = bset ? H11 : H12;

    int gq = i >> 4;
    int b = gq >> 13;
    int m = idx[i];
    float4 p = cpts[b*NN + m];
    float4 q = xyzw1[gq];
    float x = p.x - q.x, y = p.y - q.y, z = p.z - q.z;
    float h1[8], h2[8];
    #pragma unroll
    for (int j = 0; j < 8; ++j){
        float v = b1[j] + w1[j*3+0]*x + w1[j*3+1]*y + w1[j*3+2]*z;
        h1[j] = fmaxf(v, 0.f);
    }
    #pragma unroll
    for (int j = 0; j < 8; ++j){
        float v = b2[j];
        #pragma unroll
        for (int jj = 0; jj < 8; ++jj) v = fmaf(w2[j*8+jj], h1[jj], v);
        h2[j] = fmaxf(v, 0.f);
    }
    float4* o = (float4*)(H + (size_t)i*8);
    o[0] = make_float4(h2[0],h2[1],h2[2],h2[3]);
    o[1] = make_float4(h2[4],h2[5],h2[6],h2[7]);
}

__device__ __forceinline__ float rl_f(int hb, int lane_c){
    return __int_as_float(__builtin_amdgcn_readlane(hb, lane_c));
}

// ---------------- K4: fused stage 1 -> p2n[b,n,co] ----------------
__global__ __launch_bounds__(256) void k_stage1(const float* __restrict__ A1, const float* __restrict__ A2,
                                                const int* __restrict__ idx12, const float* __restrict__ H12,
                                                const float4* __restrict__ xyzw1, const float4* __restrict__ xyzw2,
                                                const float* __restrict__ W1full, const float* __restrict__ W2,
                                                const float* __restrict__ b2, const float* __restrict__ w3,
                                                const float* __restrict__ b3, float* __restrict__ p2n){
    int lane = threadIdx.x & 63;
    int wv = threadIdx.x >> 6;
    int wgid = blockIdx.x*4 + wv;

    float w2r[64];
    const float4* w2p = (const float4*)(W2 + (size_t)lane*64);
    #pragma unroll
    for (int c4 = 0; c4 < 16; ++c4){
        float4 v = w2p[c4];
        w2r[c4*4+0]=v.x; w2r[c4*4+1]=v.y; w2r[c4*4+2]=v.z; w2r[c4*4+3]=v.w;
    }
    float w1cx = W1full[lane*131+128], w1cy = W1full[lane*131+129], w1cz = W1full[lane*131+130];
    float b2v = b2[lane], b3v = b3[lane];
    float w3r[8];
    {
        const float4* w3p = (const float4*)(w3 + (size_t)lane*8);
        float4 a = w3p[0], bq = w3p[1];
        w3r[0]=a.x; w3r[1]=a.y; w3r[2]=a.z; w3r[3]=a.w;
        w3r[4]=bq.x; w3r[5]=bq.y; w3r[6]=bq.z; w3r[7]=bq.w;
    }

    for (int task = wgid; task < BN; task += 8192){
        int b = task >> 13;
        float4 q = xyzw1[task];
        float a1 = A1[(size_t)task*64 + lane];
        float acc = 0.f;
        const int* ip = idx12 + (size_t)task*16;
        for (int k = 0; k < 16; ++k){
            int m = ip[k];
            float4 p = xyzw2[b*NN + m];
            float a2 = A2[(size_t)(b*NN+m)*64 + lane];
            float h = a1 + a2;
            h = fmaf(w1cx, p.x - q.x, h);
            h = fmaf(w1cy, p.y - q.y, h);
            h = fmaf(w1cz, p.z - q.z, h);
            h = fmaxf(h, 0.1f*h);                 // leaky relu
            int hb = __float_as_int(h);
            float c20 = 0.f, c21 = 0.f, c22 = 0.f, c23 = 0.f;
            #pragma unroll
            for (int c = 0; c < 64; c += 4){
                c20 = fmaf(w2r[c+0], rl_f(hb, c+0), c20);
                c21 = fmaf(w2r[c+1], rl_f(hb, c+1), c21);
                c22 = fmaf(w2r[c+2], rl_f(hb, c+2), c22);
                c23 = fmaf(w2r[c+3], rl_f(hb, c+3), c23);
            }
            float c2 = ((c20 + c21) + (c22 + c23)) + b2v;
            c2 = fmaxf(c2, 0.1f*c2);              // leaky relu
            const float4* hw = (const float4*)(H12 + (size_t)(task*16+k)*8);
            float4 ha = hw[0], hb2 = hw[1];
            float w = b3v;
            w = fmaf(w3r[0], ha.x, w); w = fmaf(w3r[1], ha.y, w);
            w = fmaf(w3r[2], ha.z, w); w = fmaf(w3r[3], ha.w, w);
            w = fmaf(w3r[4], hb2.x, w); w = fmaf(w3r[5], hb2.y, w);
            w = fmaf(w3r[6], hb2.z, w); w = fmaf(w3r[7], hb2.w, w);
            w = fmaxf(w, 0.f);                    // relu
            acc = fmaf(w, c2, acc);
        }
        p2n[(size_t)task*64 + lane] = acc;
    }
}

// ---------------- K5: fused stage 2 -> out[b,co,n] ----------------
__global__ __launch_bounds__(256) void k_stage2(const float* __restrict__ p2n, const int* __restrict__ idx11,
                                                const float* __restrict__ H11, const float* __restrict__ w3,
                                                const float* __restrict__ b3, float* __restrict__ out){
    __shared__ float tl[64*65];
    int lane = threadIdx.x & 63;
    int wv = threadIdx.x >> 6;
    int base = blockIdx.x*64;     // flat (b,n)
    int b = base >> 13;

    float w3r[8];
    {
        const float4* w3p = (const float4*)(w3 + (size_t)lane*8);
        float4 a = w3p[0], bq = w3p[1];
        w3r[0]=a.x; w3r[1]=a.y; w3r[2]=a.z; w3r[3]=a.w;
        w3r[4]=bq.x; w3r[5]=bq.y; w3r[6]=bq.z; w3r[7]=bq.w;
    }
    float b3v = b3[lane];

    for (int i = 0; i < 16; ++i){
        int col = base + wv*16 + i;
        const int* ip = idx11 + (size_t)col*16;
        const float* Hb = H11 + (size_t)col*16*8;
        float acc = 0.f;
        for (int k = 0; k < 16; ++k){
            int m = ip[k];
            float c = p2n[(size_t)(b*NN + m)*64 + lane];
            const float4* hw = (const float4*)(Hb + k*8);
            float4 ha = hw[0], hb2 = hw[1];
            float w = b3v;
            w = fmaf(w3r[0], ha.x, w);  w = fmaf(w3r[1], ha.y, w);
            w = fmaf(w3r[2], ha.z, w);  w = fmaf(w3r[3], ha.w, w);
            w = fmaf(w3r[4], hb2.x, w); w = fmaf(w3r[5], hb2.y, w);
            w = fmaf(w3r[6], hb2.z, w); w = fmaf(w3r[7], hb2.w, w);
            w = fmaxf(w, 0.f);
            acc = fmaf(w, c, acc);
        }
        tl[(wv*16+i)*65 + lane] = acc;
    }
    __syncthreads();
    int n0 = base & (NN-1);
    #pragma unroll
    for (int i = 0; i < 16; ++i){
        int co = i*4 + wv;
        float v = tl[lane*65 + co];
        out[((size_t)b*64 + co)*NN + n0 + lane] = v;
    }
}

extern "C" void kernel_launch(void* const* d_in, const int* in_sizes, int n_in,
                              void* d_out, int out_size, void* d_ws, size_t ws_size,
                              hipStream_t stream) {
    const float* xyz1   = (const float*)d_in[0];
    const float* feat1  = (const float*)d_in[1];
    const float* xyz2   = (const float*)d_in[2];
    const float* feat2  = (const float*)d_in[3];
    const float* cost_w1 = (const float*)d_in[4];
    const float* cost_b1 = (const float*)d_in[5];
    const float* cost_w2 = (const float*)d_in[6];
    const float* cost_b2 = (const float*)d_in[7];
    const float* wn1_w1 = (const float*)d_in[8];
    const float* wn1_b1 = (const float*)d_in[9];
    const float* wn1_w2 = (const float*)d_in[10];
    const float* wn1_b2 = (const float*)d_in[11];
    const float* wn1_w3 = (const float*)d_in[12];
    const float* wn1_b3 = (const float*)d_in[13];
    const float* wn2_w1 = (const float*)d_in[14];
    const float* wn2_b1 = (const float*)d_in[15];
    const float* wn2_w2 = (const float*)d_in[16];
    const float* wn2_b2 = (const float*)d_in[17];
    const float* wn2_w3 = (const float*)d_in[18];
    const float* wn2_b3 = (const float*)d_in[19];

    char* ws = (char*)d_ws;
    float4* xyzw1 = (float4*)(ws + 0);
    float4* xyzw2 = (float4*)(ws + 524288);
    float*  A1    = (float*)(ws + 1048576);
    float*  A2    = (float*)(ws + 9437184);
    int*    idx12 = (int*)  (ws + 17825792);
    int*    idx11 = (int*)  (ws + 19922944);
    float*  H12   = (float*)(ws + 22020096);
    float*  H11   = (float*)(ws + 38797312);
    float*  p2n   = (float*)(ws + 55574528);

    k_xyzw<<<256, 256, 0, stream>>>(xyz1, xyz2, xyzw1, xyzw2);
    k_prefeat<<<256, 256, 0, stream>>>(feat1, feat2, cost_w1, cost_b1, A1, A2);
    k_knn<<<dim3(512,2), 512, 0, stream>>>(xyzw1, xyzw2, xyzw1, idx12, idx11);
    k_h2<<<4096, 256, 0, stream>>>(xyzw1, xyzw2, idx12, idx11,
                                   wn2_w1, wn2_b1, wn2_w2, wn2_b2,
                                   wn1_w1, wn1_b1, wn1_w2, wn1_b2, H12, H11);
    k_stage1<<<2048, 256, 0, stream>>>(A1, A2, idx12, H12, xyzw1, xyzw2,
                                       cost_w1, cost_w2, cost_b2, wn2_w3, wn2_b3, p2n);
    k_stage2<<<512, 256, 0, stream>>>(p2n, idx11, H11, wn1_w3, wn1_b3, (float*)d_out);
}

// Round 17
// 682.258 us; speedup vs baseline: 1.1801x; 1.1801x over previous
//
#include <hip/hip_runtime.h>
#include <stdint.h>

#define BB 4
#define NN 8192
#define KK 16
#define BN (BB*NN)        // 32768
#define BNK (BN*KK)       // 524288

// ---------------- K0: pack xyz -> (x,y,z,|p|^2) float4 ----------------
__global__ void k_xyzw(const float* __restrict__ xyz1, const float* __restrict__ xyz2,
                       float4* __restrict__ w1, float4* __restrict__ w2){
    int t = blockIdx.x*256 + threadIdx.x;
    if (t >= 2*BN) return;
    const float* src; float4* dst; int i;
    if (t < BN){ src = xyz1; dst = w1; i = t; }
    else       { src = xyz2; dst = w2; i = t - BN; }
    int b = i >> 13, m = i & (NN-1);
    const float* p = src + (size_t)b*3*NN + m;
    float x = p[0], y = p[NN], z = p[2*NN];
    dst[i] = make_float4(x, y, z, x*x + y*y + z*z);
}

// ------------- K1: merged prefeat: A[half][b,n,co] = bias + W1[:,colOff:colOff+64]*feat -------------
__global__ __launch_bounds__(256) void k_prefeat(const float* __restrict__ feat1,
                                                 const float* __restrict__ feat2,
                                                 const float* __restrict__ W1,
                                                 const float* __restrict__ bias,
                                                 float* __restrict__ A1, float* __restrict__ A2){
    __shared__ float Wt[64*64];   // [ci][co]
    __shared__ float bsh[64];
    int tid = threadIdx.x;
    int lane = tid & 63;
    int wv = tid >> 6;
    int half = blockIdx.x >> 7;                  // 0: feat1->A1 (bias), 1: feat2->A2
    int colOff = half ? 64 : 0;
    const float* feat = half ? feat2 : feat1;
    float* out = half ? A2 : A1;

    for (int i = tid; i < 4096; i += 256){
        int co = i >> 6, ci = i & 63;
        Wt[ci*64 + co] = W1[co*131 + colOff + ci];
    }
    if (tid < 64) bsh[tid] = half ? 0.0f : bias[tid];
    __syncthreads();

    int col = (blockIdx.x & 127)*256 + wv*64 + lane;   // (b,n) flat
    int b = col >> 13, n = col & (NN-1);
    const float* f = feat + (size_t)b*64*NN + n;
    float acc[64];
    #pragma unroll
    for (int co = 0; co < 64; ++co) acc[co] = 0.f;
    for (int ci = 0; ci < 64; ++ci){
        float v = f[(size_t)ci*NN];
        const float4* wrow = (const float4*)(Wt + ci*64);
        #pragma unroll
        for (int c4 = 0; c4 < 16; ++c4){
            float4 w = wrow[c4];
            acc[c4*4+0] = fmaf(w.x, v, acc[c4*4+0]);
            acc[c4*4+1] = fmaf(w.y, v, acc[c4*4+1]);
            acc[c4*4+2] = fmaf(w.z, v, acc[c4*4+2]);
            acc[c4*4+3] = fmaf(w.w, v, acc[c4*4+3]);
        }
    }
    float4* o = (float4*)(out + (size_t)col*64);
    const float4* bs = (const float4*)bsh;
    #pragma unroll
    for (int c4 = 0; c4 < 16; ++c4){
        float4 bb = bs[c4];
        o[c4] = make_float4(acc[c4*4+0]+bb.x, acc[c4*4+1]+bb.y,
                            acc[c4*4+2]+bb.z, acc[c4*4+3]+bb.w);
    }
}

// ---------------- K2: exact 16-NN (round-8 exact code, best measured 462us) ----------------
// Wave w owns chunk [1024w,1024w+1024) for the block's 64 queries (lane=query).
// Phase A: f32 threshold from 256-sample subset (stacks in LDS, fmin/fmax ladder).
// Phase B: full scan, tight threshold; survivors f64-verified into packed-u64
// register ladder (exact f64 ordering, top_k tie semantics). Branchy stack push
// (predicated store only) keeps LDS bank conflicts ~1.6e6 (branchless = 5e7, r14;
// full-chunk Phase A = +130us, r16 — cost is linear in screen evals).
#define SCAP 19
#define CHUNK 1024

__device__ __forceinline__ unsigned mono_f32(float f){
    unsigned u = __float_as_uint(f);
    return ((int)u >= 0) ? (u | 0x80000000u) : ~u;
}
__device__ __forceinline__ float unmono_f32(unsigned v){
    unsigned u = ((int)v < 0) ? (v & 0x7FFFFFFFu) : ~v;
    return __uint_as_float(u);
}
__device__ __forceinline__ unsigned long long mono_f64(double d){
    unsigned long long u = (unsigned long long)__double_as_longlong(d);
    return ((long long)u >= 0) ? (u | 0x8000000000000000ull) : ~u;
}
__device__ __forceinline__ double unmono_f64(unsigned long long v){
    unsigned long long u = ((long long)v < 0) ? (v & 0x7FFFFFFFFFFFFFFFull) : ~v;
    return __longlong_as_double((long long)u);
}

#define FSWAP(x,y) { float _a = fminf((x),(y)), _b = fmaxf((x),(y)); (x)=_a; (y)=_b; }
#define INSERT_F(t)                                                         \
    if ((t) < T15){                                                         \
        T15 = (t);                                                          \
        FSWAP(T14,T15) FSWAP(T13,T14) FSWAP(T12,T13) FSWAP(T11,T12)         \
        FSWAP(T10,T11) FSWAP(T9,T10)  FSWAP(T8,T9)   FSWAP(T7,T8)           \
        FSWAP(T6,T7)   FSWAP(T5,T6)   FSWAP(T4,T5)   FSWAP(T3,T4)           \
        FSWAP(T2,T3)   FSWAP(T1,T2)   FSWAP(T0,T1)                          \
    }

#define KSWAP(x,y) { unsigned long long _lo=(x), _hi=(y); bool _sw=_hi<_lo; (y)=_sw?_lo:_hi; (x)=_sw?_hi:_lo; }
#define INSERT_KEY(key)                                                     \
    if ((key) < A15){                                                       \
        A15 = (key);                                                        \
        KSWAP(A14,A15) KSWAP(A13,A14) KSWAP(A12,A13) KSWAP(A11,A12)         \
        KSWAP(A10,A11) KSWAP(A9,A10)  KSWAP(A8,A9)   KSWAP(A7,A8)           \
        KSWAP(A6,A7)   KSWAP(A5,A6)   KSWAP(A4,A5)   KSWAP(A3,A4)           \
        KSWAP(A2,A3)   KSWAP(A1,A2)   KSWAP(A0,A1)                          \
    }

__global__ __launch_bounds__(512, 2) void k_knn(const float4* __restrict__ qpts,
                                             const float4* __restrict__ cA, const float4* __restrict__ cB,
                                             int* __restrict__ outA, int* __restrict__ outB){
    __shared__ unsigned int thrsh[64];
    __shared__ __align__(16) char pool[38912];   // phase stacks / merge area unioned

    const float4* cpts = (blockIdx.y == 0) ? cA : cB;
    int* out            = (blockIdx.y == 0) ? outA : outB;

    int tid = threadIdx.x;
    int lane = tid & 63;
    int wv = tid >> 6;
    int gq = blockIdx.x*64 + lane;
    int b = gq >> 13;
    float4 q = qpts[gq];
    float n2x = -2.f*q.x, n2y = -2.f*q.y, n2z = -2.f*q.z;
    double qx = q.x, qy = q.y, qz = q.z;
    double qq = fma(qx,qx, fma(qy,qy, qz*qz));

    if (tid < 64) thrsh[tid] = 0xFF800000u;      // mono(+inf)
    __syncthreads();

    const float4* cb = cpts + (size_t)b*NN;
    int j0beg = wv*CHUNK;
    int cnt = 0;

    // ================= Phase A: f32 threshold from 256-sample subset =================
    {
        float T0,T1,T2,T3,T4,T5,T6,T7,T8,T9,T10,T11,T12,T13,T14,T15;
        const float FINF = __builtin_inff();
        T0=FINF;T1=FINF;T2=FINF;T3=FINF;T4=FINF;T5=FINF;T6=FINF;T7=FINF;
        T8=FINF;T9=FINF;T10=FINF;T11=FINF;T12=FINF;T13=FINF;T14=FINF;T15=FINF;
        float bdtA = FINF;
        float* stkf = ((float*)pool) + tid*SCAP;

        for (int jo = j0beg; jo < j0beg + CHUNK; jo += 16){   // 4 of every 16
            const float4* cp = cb + jo;
            #pragma unroll
            for (int jj = 0; jj < 4; ++jj){
                float4 c = cp[jj];
                float t = fmaf(n2x, c.x, c.w);
                t = fmaf(n2y, c.y, t);
                t = fmaf(n2z, c.z, t);
                if (t < fminf(bdtA, T15)){ stkf[cnt] = t; cnt++; }
            }
            if (__any(cnt >= 16)){
                for (int s = 0; s < cnt; ++s){ float t = stkf[s]; INSERT_F(t) }
                cnt = 0;
                unsigned m = mono_f32(T15);
                unsigned old = atomicMin(&thrsh[lane], m);
                bdtA = unmono_f32(old < m ? old : m);
            }
        }
        for (int s = 0; s < cnt; ++s){ float t = stkf[s]; INSERT_F(t) }
        cnt = 0;
        atomicMin(&thrsh[lane], mono_f32(T15));
    }
    __syncthreads();     // all Phase-A thresholds published

    // ================= Phase B: exact rescan, tight screen =================
    const unsigned long long KINIT = 0xFFF0000000000000ull | 8191ull;  // mono(+inf)|idx
    unsigned long long A0=KINIT, A1=KINIT, A2=KINIT, A3=KINIT,
                       A4=KINIT, A5=KINIT, A6=KINIT, A7=KINIT,
                       A8=KINIT, A9=KINIT, A10=KINIT, A11=KINIT,
                       A12=KINIT, A13=KINIT, A14=KINIT, A15=KINIT;
    float bdt = unmono_f32(thrsh[lane]) + 1e-4f;   // margin >> f32 screen error
    int* stk = ((int*)pool) + tid*SCAP;

    #define FLUSH_B()                                                            \
        do {                                                                     \
            for (int s = 0; s < cnt; ++s){                                       \
                int j = stk[s];                                                  \
                float4 c = cb[j];                                                \
                double px = c.x, py = c.y, pz = c.z;                             \
                double pp  = fma(px,px, fma(py,py, pz*pz));                      \
                double dot = fma(qx,px, fma(qy,py, qz*pz));                      \
                double d2 = qq + pp - 2.0*dot;                                   \
                unsigned long long key =                                         \
                    (mono_f64(d2) & ~8191ull) | (unsigned long long)(unsigned)j; \
                INSERT_KEY(key)                                                  \
            }                                                                    \
            cnt = 0;                                                             \
            bdt = fminf(bdt, (float)(unmono_f64(A15) - qq) + 1e-4f);             \
        } while(0)

    for (int j0 = j0beg; j0 < j0beg + CHUNK; j0 += 4){
        const float4* cp = cb + j0;
        #pragma unroll
        for (int jj = 0; jj < 4; ++jj){
            float4 c = cp[jj];
            float t = fmaf(n2x, c.x, c.w);
            t = fmaf(n2y, c.y, t);
            t = fmaf(n2z, c.z, t);
            if (t < bdt){ stk[cnt] = j0 + jj; cnt++; }
        }
        if (__any(cnt >= 16)) FLUSH_B();         // max growth 4/group, SCAP=19 safe
    }
    FLUSH_B();

    __syncthreads();                             // stacks dead; pool becomes merge area
    unsigned long long* mrg = (unsigned long long*)pool;   // [4][64][17]
    #pragma unroll
    for (int r = 4; r >= 1; r >>= 1){
        if (wv >= r && wv < 2*r){
            unsigned long long* dst = mrg + ((size_t)(wv - r)*64 + lane)*17;
            dst[0]=A0;  dst[1]=A1;  dst[2]=A2;  dst[3]=A3;
            dst[4]=A4;  dst[5]=A5;  dst[6]=A6;  dst[7]=A7;
            dst[8]=A8;  dst[9]=A9;  dst[10]=A10; dst[11]=A11;
            dst[12]=A12; dst[13]=A13; dst[14]=A14; dst[15]=A15;
        }
        __syncthreads();
        if (wv < r){
            const unsigned long long* src = mrg + ((size_t)wv*64 + lane)*17;
            for (int i = 0; i < 16; ++i){
                unsigned long long bkey = src[i];
                if (__all(bkey >= A15)) break;       // uniform early-out
                INSERT_KEY(bkey)
            }
        }
        __syncthreads();
    }
    if (wv == 0){
        int4* o = (int4*)(out + (size_t)gq*16);
        o[0] = make_int4((int)(A0 & 8191ull),  (int)(A1 & 8191ull),
                         (int)(A2 & 8191ull),  (int)(A3 & 8191ull));
        o[1] = make_int4((int)(A4 & 8191ull),  (int)(A5 & 8191ull),
                         (int)(A6 & 8191ull),  (int)(A7 & 8191ull));
        o[2] = make_int4((int)(A8 & 8191ull),  (int)(A9 & 8191ull),
                         (int)(A10 & 8191ull), (int)(A11 & 8191ull));
        o[3] = make_int4((int)(A12 & 8191ull), (int)(A13 & 8191ull),
                         (int)(A14 & 8191ull), (int)(A15 & 8191ull));
    }
}

// ---------------- K3: merged small-MLP hidden states (both neighbor sets) ----------------
__global__ __launch_bounds__(256) void k_h2(const float4* __restrict__ xyzw1, const float4* __restrict__ xyzw2,
                                            const int* __restrict__ idx12, const int* __restrict__ idx11,
                                            const float* __restrict__ w1a, const float* __restrict__ b1a,
                                            const float* __restrict__ w2a, const float* __restrict__ b2a,
                                            const float* __restrict__ w1b, const float* __restrict__ b1b,
                                            const float* __restrict__ w2b, const float* __restrict__ b2b,
                                            float* __restrict__ H12, float* __restrict__ H11){
    int bset = blockIdx.x >> 11;                 // 0: idx12 (wn2->H12), 1: idx11 (wn1->H11)
    int i = (blockIdx.x & 2047)*256 + threadIdx.x;   // over BNK
    const int* idx = bset ? idx11 : idx12;
    const float4* cpts = bset ? xyzw1 : xyzw2;
    const float* w1 = bset ? w1b : w1a;  const float* b1 = bset ? b1b : b1a;
    const float* w2 = bset ? w2b : w2a;  const float* b2 = bset ? b2b : b2a;
    float* H = bset ? H11 : H12;

    int gq = i >> 4;
    int b = gq >> 13;
    int m = idx[i];
    float4 p = cpts[b*NN + m];
    float4 q = xyzw1[gq];
    float x = p.x - q.x, y = p.y - q.y, z = p.z - q.z;
    float h1[8], h2[8];
    #pragma unroll
    for (int j = 0; j < 8; ++j){
        float v = b1[j] + w1[j*3+0]*x + w1[j*3+1]*y + w1[j*3+2]*z;
        h1[j] = fmaxf(v, 0.f);
    }
    #pragma unroll
    for (int j = 0; j < 8; ++j){
        float v = b2[j];
        #pragma unroll
        for (int jj = 0; jj < 8; ++jj) v = fmaf(w2[j*8+jj], h1[jj], v);
        h2[j] = fmaxf(v, 0.f);
    }
    float4* o = (float4*)(H + (size_t)i*8);
    o[0] = make_float4(h2[0],h2[1],h2[2],h2[3]);
    o[1] = make_float4(h2[4],h2[5],h2[6],h2[7]);
}

__device__ __forceinline__ float rl_f(int hb, int lane_c){
    return __int_as_float(__builtin_amdgcn_readlane(hb, lane_c));
}

// ---------------- K4: fused stage 1 -> p2n[b,n,co] (full-occupancy grid) ----------------
__global__ __launch_bounds__(256) void k_stage1(const float* __restrict__ A1, const float* __restrict__ A2,
                                                const int* __restrict__ idx12, const float* __restrict__ H12,
                                                const float4* __restrict__ xyzw1, const float4* __restrict__ xyzw2,
                                                const float* __restrict__ W1full, const float* __restrict__ W2,
                                                const float* __restrict__ b2, const float* __restrict__ w3,
                                                const float* __restrict__ b3, float* __restrict__ p2n){
    int lane = threadIdx.x & 63;
    int wv = threadIdx.x >> 6;
    int wgid = blockIdx.x*4 + wv;

    float w2r[64];
    const float4* w2p = (const float4*)(W2 + (size_t)lane*64);
    #pragma unroll
    for (int c4 = 0; c4 < 16; ++c4){
        float4 v = w2p[c4];
        w2r[c4*4+0]=v.x; w2r[c4*4+1]=v.y; w2r[c4*4+2]=v.z; w2r[c4*4+3]=v.w;
    }
    float w1cx = W1full[lane*131+128], w1cy = W1full[lane*131+129], w1cz = W1full[lane*131+130];
    float b2v = b2[lane], b3v = b3[lane];
    float w3r[8];
    {
        const float4* w3p = (const float4*)(w3 + (size_t)lane*8);
        float4 a = w3p[0], bq = w3p[1];
        w3r[0]=a.x; w3r[1]=a.y; w3r[2]=a.z; w3r[3]=a.w;
        w3r[4]=bq.x; w3r[5]=bq.y; w3r[6]=bq.z; w3r[7]=bq.w;
    }

    for (int task = wgid; task < BN; task += 8192){
        int b = task >> 13;
        float4 q = xyzw1[task];
        float a1 = A1[(size_t)task*64 + lane];
        float acc = 0.f;
        const int* ip = idx12 + (size_t)task*16;
        for (int k = 0; k < 16; ++k){
            int m = ip[k];
            float4 p = xyzw2[b*NN + m];
            float a2 = A2[(size_t)(b*NN+m)*64 + lane];
            float h = a1 + a2;
            h = fmaf(w1cx, p.x - q.x, h);
            h = fmaf(w1cy, p.y - q.y, h);
            h = fmaf(w1cz, p.z - q.z, h);
            h = fmaxf(h, 0.1f*h);                 // leaky relu
            int hb = __float_as_int(h);
            float c20 = 0.f, c21 = 0.f, c22 = 0.f, c23 = 0.f;
            #pragma unroll
            for (int c = 0; c < 64; c += 4){
                c20 = fmaf(w2r[c+0], rl_f(hb, c+0), c20);
                c21 = fmaf(w2r[c+1], rl_f(hb, c+1), c21);
                c22 = fmaf(w2r[c+2], rl_f(hb, c+2), c22);
                c23 = fmaf(w2r[c+3], rl_f(hb, c+3), c23);
            }
            float c2 = ((c20 + c21) + (c22 + c23)) + b2v;
            c2 = fmaxf(c2, 0.1f*c2);              // leaky relu
            const float4* hw = (const float4*)(H12 + (size_t)(task*16+k)*8);
            float4 ha = hw[0], hb2 = hw[1];
            float w = b3v;
            w = fmaf(w3r[0], ha.x, w); w = fmaf(w3r[1], ha.y, w);
            w = fmaf(w3r[2], ha.z, w); w = fmaf(w3r[3], ha.w, w);
            w = fmaf(w3r[4], hb2.x, w); w = fmaf(w3r[5], hb2.y, w);
            w = fmaf(w3r[6], hb2.z, w); w = fmaf(w3r[7], hb2.w, w);
            w = fmaxf(w, 0.f);                    // relu
            acc = fmaf(w, c2, acc);
        }
        p2n[(size_t)task*64 + lane] = acc;
    }
}

// ---------------- K5: fused stage 2 -> out[b,co,n] ----------------
__global__ __launch_bounds__(256) void k_stage2(const float* __restrict__ p2n, const int* __restrict__ idx11,
                                                const float* __restrict__ H11, const float* __restrict__ w3,
                                                const float* __restrict__ b3, float* __restrict__ out){
    __shared__ float tl[64*65];
    int lane = threadIdx.x & 63;
    int wv = threadIdx.x >> 6;
    int base = blockIdx.x*64;     // flat (b,n)
    int b = base >> 13;

    float w3r[8];
    {
        const float4* w3p = (const float4*)(w3 + (size_t)lane*8);
        float4 a = w3p[0], bq = w3p[1];
        w3r[0]=a.x; w3r[1]=a.y; w3r[2]=a.z; w3r[3]=a.w;
        w3r[4]=bq.x; w3r[5]=bq.y; w3r[6]=bq.z; w3r[7]=bq.w;
    }
    float b3v = b3[lane];

    for (int i = 0; i < 16; ++i){
        int col = base + wv*16 + i;
        const int* ip = idx11 + (size_t)col*16;
        const float* Hb = H11 + (size_t)col*16*8;
        float acc = 0.f;
        for (int k = 0; k < 16; ++k){
            int m = ip[k];
            float c = p2n[(size_t)(b*NN + m)*64 + lane];
            const float4* hw = (const float4*)(Hb + k*8);
            float4 ha = hw[0], hb2 = hw[1];
            float w = b3v;
            w = fmaf(w3r[0], ha.x, w);  w = fmaf(w3r[1], ha.y, w);
            w = fmaf(w3r[2], ha.z, w);  w = fmaf(w3r[3], ha.w, w);
            w = fmaf(w3r[4], hb2.x, w); w = fmaf(w3r[5], hb2.y, w);
            w = fmaf(w3r[6], hb2.z, w); w = fmaf(w3r[7], hb2.w, w);
            w = fmaxf(w, 0.f);
            acc = fmaf(w, c, acc);
        }
        tl[(wv*16+i)*65 + lane] = acc;
    }
    __syncthreads();
    int n0 = base & (NN-1);
    #pragma unroll
    for (int i = 0; i < 16; ++i){
        int co = i*4 + wv;
        float v = tl[lane*65 + co];
        out[((size_t)b*64 + co)*NN + n0 + lane] = v;
    }
}

extern "C" void kernel_launch(void* const* d_in, const int* in_sizes, int n_in,
                              void* d_out, int out_size, void* d_ws, size_t ws_size,
                              hipStream_t stream) {
    const float* xyz1   = (const float*)d_in[0];
    const float* feat1  = (const float*)d_in[1];
    const float* xyz2   = (const float*)d_in[2];
    const float* feat2  = (const float*)d_in[3];
    const float* cost_w1 = (const float*)d_in[4];
    const float* cost_b1 = (const float*)d_in[5];
    const float* cost_w2 = (const float*)d_in[6];
    const float* cost_b2 = (const float*)d_in[7];
    const float* wn1_w1 = (const float*)d_in[8];
    const float* wn1_b1 = (const float*)d_in[9];
    const float* wn1_w2 = (const float*)d_in[10];
    const float* wn1_b2 = (const float*)d_in[11];
    const float* wn1_w3 = (const float*)d_in[12];
    const float* wn1_b3 = (const float*)d_in[13];
    const float* wn2_w1 = (const float*)d_in[14];
    const float* wn2_b1 = (const float*)d_in[15];
    const float* wn2_w2 = (const float*)d_in[16];
    const float* wn2_b2 = (const float*)d_in[17];
    const float* wn2_w3 = (const float*)d_in[18];
    const float* wn2_b3 = (const float*)d_in[19];

    char* ws = (char*)d_ws;
    float4* xyzw1 = (float4*)(ws + 0);
    float4* xyzw2 = (float4*)(ws + 524288);
    float*  A1    = (float*)(ws + 1048576);
    float*  A2    = (float*)(ws + 9437184);
    int*    idx12 = (int*)  (ws + 17825792);
    int*    idx11 = (int*)  (ws + 19922944);
    float*  H12   = (float*)(ws + 22020096);
    float*  H11   = (float*)(ws + 38797312);
    float*  p2n   = (float*)(ws + 55574528);

    k_xyzw<<<256, 256, 0, stream>>>(xyz1, xyz2, xyzw1, xyzw2);
    k_prefeat<<<256, 256, 0, stream>>>(feat1, feat2, cost_w1, cost_b1, A1, A2);
    k_knn<<<dim3(512,2), 512, 0, stream>>>(xyzw1, xyzw2, xyzw1, idx12, idx11);
    k_h2<<<4096, 256, 0, stream>>>(xyzw1, xyzw2, idx12, idx11,
                                   wn2_w1, wn2_b1, wn2_w2, wn2_b2,
                                   wn1_w1, wn1_b1, wn1_w2, wn1_b2, H12, H11);
    k_stage1<<<2048, 256, 0, stream>>>(A1, A2, idx12, H12, xyzw1, xyzw2,
                                       cost_w1, cost_w2, cost_b2, wn2_w3, wn2_b3, p2n);
    k_stage2<<<512, 256, 0, stream>>>(p2n, idx11, H11, wn1_w3, wn1_b3, (float*)d_out);
}